// Round 1
// baseline (1364.862 us; speedup 1.0000x reference)
//
#include <hip/hip_runtime.h>
#include <hip/hip_bf16.h>
#include <math.h>

#define DIM   5120
#define QD    8192      // N_HEADS*HEAD_DIM
#define KVD   1024      // N_KV*HEAD_DIM
#define NH    64
#define NKV   8
#define HD    128
#define HID   25600
#define SEQL  1024
#define BSZ   32

__device__ __forceinline__ float fma4(float4 a, float4 b, float acc) {
  acc = fmaf(a.x, b.x, acc);
  acc = fmaf(a.y, b.y, acc);
  acc = fmaf(a.z, b.z, acc);
  acc = fmaf(a.w, b.w, acc);
  return acc;
}

// ---------------- RMSNorm: one block per batch row (DIM=5120) ----------------
__global__ __launch_bounds__(256) void rmsnorm_kernel(
    const float* __restrict__ x, const float* __restrict__ w,
    float* __restrict__ out, float eps) {
  int b = blockIdx.x, t = threadIdx.x;
  const float4* xp = reinterpret_cast<const float4*>(x + (size_t)b * DIM);
  const float4* wp = reinterpret_cast<const float4*>(w);
  float4* op = reinterpret_cast<float4*>(out + (size_t)b * DIM);
  float4 v[5];
  float ss = 0.f;
#pragma unroll
  for (int j = 0; j < 5; ++j) {
    v[j] = xp[t + j * 256];
    ss = fma4(v[j], v[j], ss);
  }
#pragma unroll
  for (int m = 1; m < 64; m <<= 1) ss += __shfl_xor(ss, m);
  __shared__ float red[4];
  if ((t & 63) == 0) red[t >> 6] = ss;
  __syncthreads();
  float sc = rsqrtf((red[0] + red[1] + red[2] + red[3]) * (1.f / DIM) + eps);
#pragma unroll
  for (int j = 0; j < 5; ++j) {
    float4 wv = wp[t + j * 256];
    float4 o;
    o.x = v[j].x * sc * wv.x;
    o.y = v[j].y * sc * wv.y;
    o.z = v[j].z * sc * wv.z;
    o.w = v[j].w * sc * wv.w;
    op[t + j * 256] = o;
  }
}

// ---------------- Skinny GEMM: out[b][n] = sum_k A[b][k]*W[n][k] (+resid) ----
// Block: 8 rows of W x all 32 batches. Thread (bg = t&3 -> 8 batches,
// ks = t>>2 -> 4-float k-strip of a 256-float K chunk). A stays in registers
// so each W element is read once from HBM and each A element ~once per block.
template <int RESID>
__global__ __launch_bounds__(256) void gemv_kernel(
    const float* __restrict__ A, const float* __restrict__ W,
    const float* __restrict__ resid, float* __restrict__ out,
    int K, int N) {
  int t = threadIdx.x;
  int bg = t & 3;
  int ks = t >> 2;
  size_t n0 = (size_t)blockIdx.x * 8;
  const float* Wp = W + n0 * K;
  float acc[8][8];
#pragma unroll
  for (int i = 0; i < 8; ++i)
#pragma unroll
    for (int r = 0; r < 8; ++r) acc[i][r] = 0.f;
  for (int kc = 0; kc < K; kc += 256) {
    int ko = kc + ks * 4;
    float4 av[8];
#pragma unroll
    for (int i = 0; i < 8; ++i)
      av[i] = *reinterpret_cast<const float4*>(A + (size_t)(bg * 8 + i) * K + ko);
#pragma unroll
    for (int r = 0; r < 8; ++r) {
      float4 wv = *reinterpret_cast<const float4*>(Wp + (size_t)r * K + ko);
#pragma unroll
      for (int i = 0; i < 8; ++i) acc[i][r] = fma4(av[i], wv, acc[i][r]);
    }
  }
  // reduce over ks within each wave (ks low bits are t bits 2..5)
#pragma unroll
  for (int i = 0; i < 8; ++i)
#pragma unroll
    for (int r = 0; r < 8; ++r) {
      float s = acc[i][r];
      s += __shfl_xor(s, 4);
      s += __shfl_xor(s, 8);
      s += __shfl_xor(s, 16);
      s += __shfl_xor(s, 32);
      acc[i][r] = s;
    }
  __shared__ float red[4][4][64];  // [wave][bg][b_in_group*8 + r]
  if ((t & 60) == 0) {
    int wv_i = t >> 6;
#pragma unroll
    for (int i = 0; i < 8; ++i)
#pragma unroll
      for (int r = 0; r < 8; ++r) red[wv_i][bg][i * 8 + r] = acc[i][r];
  }
  __syncthreads();
  int b = t >> 3, r = t & 7;
  int bgi = b >> 3, ii = (b & 7) * 8 + r;
  float s = red[0][bgi][ii] + red[1][bgi][ii] + red[2][bgi][ii] + red[3][bgi][ii];
  size_t oi = (size_t)b * N + n0 + r;
  if (RESID) s += resid[oi];
  out[oi] = s;
}

// ---------------- per-head RMSNorm(eps=1e-6) + RoPE, in place ----------------
// grid.x: 0..63 -> q heads, 64..71 -> kv heads; grid.y = batch; 64 threads.
__global__ __launch_bounds__(64) void qknorm_rope_kernel(
    float* __restrict__ xq, float* __restrict__ xk,
    const float* __restrict__ qw, const float* __restrict__ kw,
    const float* __restrict__ fcos, const float* __restrict__ fsin) {
  int h = blockIdx.x, b = blockIdx.y, j = threadIdx.x;
  float* p;
  const float* w;
  if (h < NH) { p = xq + ((size_t)b * NH + h) * HD; w = qw; }
  else        { p = xk + ((size_t)b * NKV + (h - NH)) * HD; w = kw; }
  float x0 = p[2 * j], x1 = p[2 * j + 1];
  float ss = x0 * x0 + x1 * x1;
#pragma unroll
  for (int m = 1; m < 64; m <<= 1) ss += __shfl_xor(ss, m);
  float sc = rsqrtf(ss * (1.f / HD) + 1e-6f);
  float n0 = x0 * sc * w[2 * j];
  float n1 = x1 * sc * w[2 * j + 1];
  float c = fcos[j], s = fsin[j];
  p[2 * j]     = n0 * c - n1 * s;
  p[2 * j + 1] = n0 * s + n1 * c;
}

// ---------------- flash GQA attention: grid (g=8, b=32), 256 threads --------
// 8 q-heads share one KV group -> KV read once per block. Online softmax.
// l==1023 comes from the freshly computed (normed+roped) k / raw v, NOT from
// the (unmodified) cache inputs.
__global__ __launch_bounds__(256) void attn_kernel(
    const float* __restrict__ xq, const float* __restrict__ xk,
    const float* __restrict__ xv, const float* __restrict__ ck,
    const float* __restrict__ cv, float* __restrict__ out) {
  int g = blockIdx.x, b = blockIdx.y, t = threadIdx.x;
  __shared__ float qs[8][128];
  __shared__ float tk[128][33];   // transposed K tile [d][l], conflict-free reads
  __shared__ float tv[32][132];   // V tile [l][d], float4-aligned rows
  __shared__ float st[8][32];
  __shared__ float m_s[8], sum_s[8], fac_s[8];
  for (int i = t; i < 8 * 128; i += 256)
    qs[i >> 7][i & 127] = xq[((size_t)b * NH + g * 8 + (i >> 7)) * HD + (i & 127)];
  if (t < 8) { m_s[t] = -1e30f; sum_s[t] = 0.f; }
  int r = t >> 5, d5 = t & 31;
  float4 acc = make_float4(0.f, 0.f, 0.f, 0.f);
  for (int ti = 0; ti < 32; ++ti) {
    int l0 = ti * 32;
    __syncthreads();
#pragma unroll
    for (int jj = 0; jj < 4; ++jj) {
      int i = t + jj * 256;
      int l = i >> 5, d4 = i & 31;
      int gl = l0 + l;
      float4 kv, vv;
      if (gl == 1023) {
        kv = *reinterpret_cast<const float4*>(xk + ((size_t)b * NKV + g) * HD + d4 * 4);
        vv = *reinterpret_cast<const float4*>(xv + ((size_t)b * NKV + g) * HD + d4 * 4);
      } else {
        size_t base = (((size_t)b * SEQL + gl) * NKV + g) * HD + d4 * 4;
        kv = *reinterpret_cast<const float4*>(ck + base);
        vv = *reinterpret_cast<const float4*>(cv + base);
      }
      tk[d4 * 4 + 0][l] = kv.x;
      tk[d4 * 4 + 1][l] = kv.y;
      tk[d4 * 4 + 2][l] = kv.z;
      tk[d4 * 4 + 3][l] = kv.w;
      *reinterpret_cast<float4*>(&tv[l][d4 * 4]) = vv;
    }
    __syncthreads();
    {
      int l = t & 31, rr = t >> 5;
      float s = 0.f;
#pragma unroll 8
      for (int d = 0; d < 128; ++d) s = fmaf(qs[rr][d], tk[d][l], s);
      st[rr][l] = s * 0.08838834764831845f;  // 1/sqrt(128)
    }
    __syncthreads();
    {
      float sv = st[r][d5];
      float tm = sv;
#pragma unroll
      for (int m = 1; m < 32; m <<= 1) tm = fmaxf(tm, __shfl_xor(tm, m));
      float mo = m_s[r];
      float mn = fmaxf(mo, tm);
      float fac = __expf(mo - mn);
      float e = __expf(sv - mn);
      st[r][d5] = e;
      float ps = e;
#pragma unroll
      for (int m = 1; m < 32; m <<= 1) ps += __shfl_xor(ps, m);
      if (d5 == 0) {
        sum_s[r] = sum_s[r] * fac + ps;
        m_s[r] = mn;
        fac_s[r] = fac;
      }
    }
    __syncthreads();
    {
      float fac = fac_s[r];
      acc.x *= fac; acc.y *= fac; acc.z *= fac; acc.w *= fac;
#pragma unroll 4
      for (int l = 0; l < 32; ++l) {
        float p = st[r][l];
        float4 vv = *reinterpret_cast<const float4*>(&tv[l][d5 * 4]);
        acc.x = fmaf(p, vv.x, acc.x);
        acc.y = fmaf(p, vv.y, acc.y);
        acc.z = fmaf(p, vv.z, acc.z);
        acc.w = fmaf(p, vv.w, acc.w);
      }
    }
  }
  float inv = 1.f / sum_s[r];
  float4 o = make_float4(acc.x * inv, acc.y * inv, acc.z * inv, acc.w * inv);
  *reinterpret_cast<float4*>(out + ((size_t)b * NH + g * 8 + r) * HD + d5 * 4) = o;
}

// ---------------- SwiGLU combine ----------------
__global__ __launch_bounds__(256) void silu_mul_kernel(
    const float* __restrict__ g1, const float* __restrict__ g3,
    float* __restrict__ g, int n) {
  int i = blockIdx.x * 256 + threadIdx.x;
  if (i < n) {
    float a = g1[i];
    g[i] = (a / (1.f + __expf(-a))) * g3[i];
  }
}

extern "C" void kernel_launch(void* const* d_in, const int* in_sizes, int n_in,
                              void* d_out, int out_size, void* d_ws, size_t ws_size,
                              hipStream_t stream) {
  const float* x    = (const float*)d_in[0];
  // d_in[1] start_pos == 1023 (fixed by problem); d_in[4] mask == zeros.
  const float* fcos = (const float*)d_in[2];
  const float* fsin = (const float*)d_in[3];
  const float* ck   = (const float*)d_in[5];
  const float* cv   = (const float*)d_in[6];
  const float* wq   = (const float*)d_in[7];
  const float* wk   = (const float*)d_in[8];
  const float* wv   = (const float*)d_in[9];
  const float* wo   = (const float*)d_in[10];
  const float* w1   = (const float*)d_in[11];
  const float* w2   = (const float*)d_in[12];
  const float* w3   = (const float*)d_in[13];
  const float* anw  = (const float*)d_in[14];
  const float* fnw  = (const float*)d_in[15];
  const float* qnw  = (const float*)d_in[16];
  const float* knw  = (const float*)d_in[17];
  float* out = (float*)d_out;

  // workspace carve-up (~14.2 MB of f32)
  float* ws = (float*)d_ws;
  float* an  = ws; ws += BSZ * DIM;
  float* xqb = ws; ws += BSZ * QD;
  float* xkb = ws; ws += BSZ * KVD;
  float* xvb = ws; ws += BSZ * KVD;
  float* ao  = ws; ws += BSZ * QD;
  float* h   = ws; ws += BSZ * DIM;
  float* fn  = ws; ws += BSZ * DIM;
  float* g1  = ws; ws += BSZ * HID;
  float* g3  = ws; ws += BSZ * HID;
  float* gg  = ws; ws += BSZ * HID;

  rmsnorm_kernel<<<BSZ, 256, 0, stream>>>(x, anw, an, 1e-5f);
  gemv_kernel<0><<<QD / 8, 256, 0, stream>>>(an, wq, nullptr, xqb, DIM, QD);
  gemv_kernel<0><<<KVD / 8, 256, 0, stream>>>(an, wk, nullptr, xkb, DIM, KVD);
  gemv_kernel<0><<<KVD / 8, 256, 0, stream>>>(an, wv, nullptr, xvb, DIM, KVD);
  qknorm_rope_kernel<<<dim3(NH + NKV, BSZ), 64, 0, stream>>>(xqb, xkb, qnw, knw, fcos, fsin);
  attn_kernel<<<dim3(NKV, BSZ), 256, 0, stream>>>(xqb, xkb, xvb, ck, cv, ao);
  gemv_kernel<1><<<DIM / 8, 256, 0, stream>>>(ao, wo, x, h, QD, DIM);
  rmsnorm_kernel<<<BSZ, 256, 0, stream>>>(h, fnw, fn, 1e-5f);
  gemv_kernel<0><<<HID / 8, 256, 0, stream>>>(fn, w1, nullptr, g1, DIM, HID);
  gemv_kernel<0><<<HID / 8, 256, 0, stream>>>(fn, w3, nullptr, g3, DIM, HID);
  silu_mul_kernel<<<(BSZ * HID + 255) / 256, 256, 0, stream>>>(g1, g3, gg, BSZ * HID);
  gemv_kernel<1><<<DIM / 8, 256, 0, stream>>>(gg, w2, h, out, HID, DIM);
}